// Round 1
// baseline (894.077 us; speedup 1.0000x reference)
//
#include <hip/hip_runtime.h>

// LinearLIFBlock: cur = einsum('tbf,of->tbo', x, W); then LIF scan over t:
//   h = v + (cur - v)/2 ; s = (h >= 1) ; v = h*(1-s)
// Output: spikes [T,B,F_out] fp32 in {0,1}.
//
// Correctness note: output is binary; a single spike flip = absmax 1.0 fail.
// So the GEMM + scan run in fp64 (error ~1e-13 vs np-f64 ref) this round.

#define T_DIM 64
#define B_DIM 256
#define F_DIM 1024
#define K_DIM 1024
#define TILE  64
#define KC    32
#define XS_LD 36   // 32 + 4 pad: keeps float4 16B alignment, breaks bank conflicts
#define SC_LD 65   // scan buffer leading dim (doubles)

__global__ __launch_bounds__(256) void lif_fused_kernel(
    const float* __restrict__ x,    // [T][B][F] = [64][256][1024]
    const float* __restrict__ Wm,   // [O][K]    = [1024][1024]
    float* __restrict__ out)        // [T][B][F] spikes
{
    // 33280 B shared: staging (2*64*36*4 = 18432 B as float) then scan buf (64*65*8 B as double)
    __shared__ __align__(16) unsigned char smem_raw[TILE * SC_LD * sizeof(double)];
    float*  sf = reinterpret_cast<float*>(smem_raw);
    double* sd = reinterpret_cast<double*>(smem_raw);
    float* Xs = sf;                  // [64][XS_LD]
    float* Ws = sf + TILE * XS_LD;   // [64][XS_LD]

    const int b   = blockIdx.y;        // batch index, 0..255
    const int o0  = blockIdx.x * TILE; // output-feature tile base
    const int tid = threadIdx.x;       // 0..255
    const int tx  = tid & 15;          // 0..15 -> 4 output cols
    const int ty  = tid >> 4;          // 0..15 -> 4 output rows (t)

    double acc[4][4];
#pragma unroll
    for (int i = 0; i < 4; ++i)
#pragma unroll
        for (int j = 0; j < 4; ++j) acc[i][j] = 0.0;

    const int r  = tid >> 3;        // 0..31: staging row
    const int c4 = (tid & 7) * 4;   // float offset within K-chunk

    const float* xbase = x + (size_t)b * F_DIM;  // x[t][b][k] = xbase + t*B*F + k

    for (int k0 = 0; k0 < K_DIM; k0 += KC) {
        __syncthreads();
        // Stage X tile: rows are t = 0..63 (row stride B*F in global)
        {
            float4 xv0 = *reinterpret_cast<const float4*>(
                xbase + (size_t)r * (B_DIM * F_DIM) + k0 + c4);
            float4 xv1 = *reinterpret_cast<const float4*>(
                xbase + (size_t)(r + 32) * (B_DIM * F_DIM) + k0 + c4);
            *reinterpret_cast<float4*>(Xs + r * XS_LD + c4) = xv0;
            *reinterpret_cast<float4*>(Xs + (r + 32) * XS_LD + c4) = xv1;
            // Stage W tile: rows are o = o0..o0+63 (row stride K)
            float4 wv0 = *reinterpret_cast<const float4*>(
                Wm + (size_t)(o0 + r) * K_DIM + k0 + c4);
            float4 wv1 = *reinterpret_cast<const float4*>(
                Wm + (size_t)(o0 + r + 32) * K_DIM + k0 + c4);
            *reinterpret_cast<float4*>(Ws + r * XS_LD + c4) = wv0;
            *reinterpret_cast<float4*>(Ws + (r + 32) * XS_LD + c4) = wv1;
        }
        __syncthreads();

#pragma unroll 4
        for (int kk = 0; kk < KC; ++kk) {
            double xa[4], wb[4];
#pragma unroll
            for (int i = 0; i < 4; ++i)
                xa[i] = (double)Xs[(4 * ty + i) * XS_LD + kk];
#pragma unroll
            for (int j = 0; j < 4; ++j)
                wb[j] = (double)Ws[(4 * tx + j) * XS_LD + kk];
#pragma unroll
            for (int i = 0; i < 4; ++i)
#pragma unroll
                for (int j = 0; j < 4; ++j)
                    acc[i][j] = fma(xa[i], wb[j], acc[i][j]);
        }
    }

    // Drop the 64x64 fp64 cur-tile into LDS for the scan
    __syncthreads();
#pragma unroll
    for (int i = 0; i < 4; ++i)
#pragma unroll
        for (int j = 0; j < 4; ++j)
            sd[(4 * ty + i) * SC_LD + (4 * tx + j)] = acc[i][j];
    __syncthreads();

    // LIF scan: one thread per output feature column, serial over t
    if (tid < TILE) {
        const int o = tid;
        double v = 0.0;
        float* outp = out + (size_t)b * F_DIM + o0 + o;
        for (int t = 0; t < T_DIM; ++t) {
            double cur = sd[t * SC_LD + o];
            double h = v + (cur - v) * 0.5;     // tau = 2.0 (exact *0.5)
            bool s = (h >= 1.0);
            outp[(size_t)t * (B_DIM * F_DIM)] = s ? 1.0f : 0.0f;
            v = s ? 0.0 : h;                    // hard reset
        }
    }
}

extern "C" void kernel_launch(void* const* d_in, const int* in_sizes, int n_in,
                              void* d_out, int out_size, void* d_ws, size_t ws_size,
                              hipStream_t stream) {
    const float* x  = (const float*)d_in[0];  // [64][256][1024]
    const float* Wm = (const float*)d_in[1];  // [1024][1024]
    float* out = (float*)d_out;               // [64][256][1024]

    dim3 grid(F_DIM / TILE, B_DIM, 1);  // (16, 256)
    dim3 block(256, 1, 1);
    lif_fused_kernel<<<grid, block, 0, stream>>>(x, Wm, out);
}

// Round 2
// 332.155 us; speedup vs baseline: 2.6917x; 2.6917x over previous
//
#include <hip/hip_runtime.h>

// LinearLIFBlock: cur = X[16384x1024] * W^T[1024x1024]; LIF scan over t (64 steps).
// Strategy: 3-term bf16 split GEMM on MFMA (cur error <~1e-5), fp32 scan with
// margin-flagging (|h-1| < 1.5e-4), exact fp64 recompute of flagged columns.
// Fallback to full-fp64 fused kernel if workspace is too small.

#define T_DIM 64
#define B_DIM 256
#define F_DIM 1024
#define K_DIM 1024
#define M_DIM 16384            // T*B
#define COLS  (B_DIM * F_DIM)  // 262144 scan columns
#define MARGIN 1.5e-4f
#define LIST_CAP 32768

typedef __attribute__((ext_vector_type(8))) short short8;
typedef __attribute__((ext_vector_type(4))) float floatx4;

#define ASYNC_CP16(gp, lp)                                                     \
    __builtin_amdgcn_global_load_lds(                                          \
        (const __attribute__((address_space(1))) unsigned int*)(gp),           \
        (__attribute__((address_space(3))) unsigned int*)(lp), 16, 0, 0)

// ---------------------------------------------------------------- bf16 split
__device__ inline unsigned short f32_to_bf16_rne(float f) {
    unsigned int u = __builtin_bit_cast(unsigned int, f);
    unsigned int r = (u + 0x7FFFu + ((u >> 16) & 1u)) >> 16;
    return (unsigned short)r;
}
__device__ inline float bf16_to_f32(unsigned short h) {
    unsigned int u = ((unsigned int)h) << 16;
    return __builtin_bit_cast(float, u);
}

__global__ __launch_bounds__(256) void split_kernel(
    const float* __restrict__ in, unsigned short* __restrict__ hi,
    unsigned short* __restrict__ lo, int n4)
{
    int i = blockIdx.x * 256 + threadIdx.x;
    if (i >= n4) return;
    float4 v = reinterpret_cast<const float4*>(in)[i];
    ushort4 h, l;
    float f;
    f = v.x; h.x = f32_to_bf16_rne(f); l.x = f32_to_bf16_rne(f - bf16_to_f32(h.x));
    f = v.y; h.y = f32_to_bf16_rne(f); l.y = f32_to_bf16_rne(f - bf16_to_f32(h.y));
    f = v.z; h.z = f32_to_bf16_rne(f); l.z = f32_to_bf16_rne(f - bf16_to_f32(h.z));
    f = v.w; h.w = f32_to_bf16_rne(f); l.w = f32_to_bf16_rne(f - bf16_to_f32(h.w));
    reinterpret_cast<ushort4*>(hi)[i] = h;
    reinterpret_cast<ushort4*>(lo)[i] = l;
}

// ------------------------------------------------------------- MFMA 3-pass GEMM
// cur[m][o] = sum_k X[m][k]*W[o][k] via (x_hi,w_hi)+(x_lo,w_hi)+(x_hi,w_lo)
__global__ __launch_bounds__(256) void gemm3_kernel(
    const unsigned short* __restrict__ x_hi, const unsigned short* __restrict__ x_lo,
    const unsigned short* __restrict__ w_hi, const unsigned short* __restrict__ w_lo,
    float* __restrict__ cur)
{
    __shared__ unsigned short As[128 * 32];  // 8 KB
    __shared__ unsigned short Bs[128 * 32];  // 8 KB

    const int tid  = threadIdx.x;
    const int lane = tid & 63;
    const int wv   = tid >> 6;
    const int m0   = blockIdx.y * 128;
    const int n0   = blockIdx.x * 128;
    const int wm   = (wv & 1) * 64;
    const int wn   = (wv >> 1) * 64;

    floatx4 acc[4][4] = {};

    const int srow = tid >> 2;            // 0..63 staging row
    const int scol = (tid & 3) * 8;       // bf16 element offset (16B chunks)
    const int lrow = lane & 15;
    const int lk   = (lane >> 4) * 8;

    const unsigned short* Aph[3] = {x_hi, x_lo, x_hi};
    const unsigned short* Bph[3] = {w_hi, w_hi, w_lo};

    for (int p = 0; p < 3; ++p) {
        const unsigned short* Ap = Aph[p] + (size_t)m0 * K_DIM;
        const unsigned short* Bp = Bph[p] + (size_t)n0 * K_DIM;
        for (int k0 = 0; k0 < K_DIM; k0 += 32) {
            __syncthreads();  // LDS reuse guard
            ASYNC_CP16(Ap + (size_t)srow * K_DIM + k0 + scol,        As + srow * 32 + scol);
            ASYNC_CP16(Ap + (size_t)(srow + 64) * K_DIM + k0 + scol, As + (srow + 64) * 32 + scol);
            ASYNC_CP16(Bp + (size_t)srow * K_DIM + k0 + scol,        Bs + srow * 32 + scol);
            ASYNC_CP16(Bp + (size_t)(srow + 64) * K_DIM + k0 + scol, Bs + (srow + 64) * 32 + scol);
            __syncthreads();

            short8 a[4], b[4];
#pragma unroll
            for (int i = 0; i < 4; ++i)
                a[i] = *reinterpret_cast<const short8*>(&As[(wm + i * 16 + lrow) * 32 + lk]);
#pragma unroll
            for (int j = 0; j < 4; ++j)
                b[j] = *reinterpret_cast<const short8*>(&Bs[(wn + j * 16 + lrow) * 32 + lk]);
#pragma unroll
            for (int i = 0; i < 4; ++i)
#pragma unroll
                for (int j = 0; j < 4; ++j)
                    acc[i][j] = __builtin_amdgcn_mfma_f32_16x16x32_bf16(a[i], b[j], acc[i][j], 0, 0, 0);
        }
    }

    // Epilogue: C/D layout col=lane&15, row=(lane>>4)*4+reg
    const int col = lane & 15;
    const int rb  = (lane >> 4) * 4;
#pragma unroll
    for (int i = 0; i < 4; ++i)
#pragma unroll
        for (int j = 0; j < 4; ++j)
#pragma unroll
            for (int r = 0; r < 4; ++r)
                cur[(size_t)(m0 + wm + i * 16 + rb + r) * F_DIM + (n0 + wn + j * 16 + col)] = acc[i][j][r];
}

// ---------------------------------------------------------------- scan + flag
__global__ __launch_bounds__(256) void zero_counter_kernel(unsigned int* counter) {
    if (threadIdx.x == 0 && blockIdx.x == 0) *counter = 0;
}

__global__ __launch_bounds__(256) void scan_kernel(
    const float* __restrict__ cur, float* __restrict__ out,
    unsigned int* __restrict__ counter, unsigned int* __restrict__ list)
{
    const int c = blockIdx.x * 256 + threadIdx.x;  // c = b*F + o
    float v = 0.f;
    bool flag = false;
    const float* cp = cur + c;
    float* op = out + c;
#pragma unroll 4
    for (int t = 0; t < T_DIM; ++t) {
        float cu = cp[(size_t)t * COLS];
        float h = v + (cu - v) * 0.5f;
        float d = h - 1.0f;
        bool s = (d >= 0.f);
        flag |= (fabsf(d) < MARGIN);
        op[(size_t)t * COLS] = s ? 1.0f : 0.0f;
        v = s ? 0.f : h;
    }
    if (flag) {
        unsigned int idx = atomicAdd(counter, 1u);
        if (idx < LIST_CAP) list[idx] = (unsigned int)c;
    }
}

// ------------------------------------------------------- exact fp64 fixup
__global__ __launch_bounds__(256) void fixup_kernel(
    const float* __restrict__ x, const float* __restrict__ W,
    const unsigned int* __restrict__ counter, const unsigned int* __restrict__ list,
    float* __restrict__ out)
{
    __shared__ double curd[T_DIM];
    __shared__ float wrow[K_DIM];
    unsigned int n = *counter;
    if (n > LIST_CAP) n = LIST_CAP;
    const int wv = threadIdx.x >> 6, lane = threadIdx.x & 63;

    for (unsigned int idx = blockIdx.x; idx < n; idx += gridDim.x) {
        const unsigned int c = list[idx];
        const int b = c >> 10, o = c & 1023;
        __syncthreads();
        for (int k = threadIdx.x; k < K_DIM; k += 256) wrow[k] = W[(size_t)o * K_DIM + k];
        __syncthreads();
        for (int it = 0; it < 16; ++it) {
            const int t = it * 4 + wv;
            const float* xp = x + (size_t)t * COLS + (size_t)b * F_DIM + lane * 16;
            const float* wp = wrow + lane * 16;
            double s = 0.0;
#pragma unroll
            for (int q = 0; q < 4; ++q) {
                float4 xv = reinterpret_cast<const float4*>(xp)[q];
                float4 wq = reinterpret_cast<const float4*>(wp)[q];
                s += (double)xv.x * (double)wq.x + (double)xv.y * (double)wq.y +
                     (double)xv.z * (double)wq.z + (double)xv.w * (double)wq.w;
            }
#pragma unroll
            for (int off = 32; off > 0; off >>= 1) s += __shfl_down(s, off, 64);
            if (lane == 0) curd[t] = s;
        }
        __syncthreads();
        if (threadIdx.x == 0) {
            double v = 0.0;
            for (int t = 0; t < T_DIM; ++t) {
                double h = v + (curd[t] - v) * 0.5;
                bool s = (h >= 1.0);
                out[(size_t)t * COLS + c] = s ? 1.0f : 0.0f;
                v = s ? 0.0 : h;
            }
        }
        __syncthreads();
    }
}

// --------------------------------------------------- fp64 fallback (round-1)
#define TILE 64
#define KC 32
#define XS_LD 36
#define SC_LD 65

__global__ __launch_bounds__(256) void lif_fused_kernel(
    const float* __restrict__ x, const float* __restrict__ Wm, float* __restrict__ out)
{
    __shared__ __align__(16) unsigned char smem_raw[TILE * SC_LD * sizeof(double)];
    float* sf = reinterpret_cast<float*>(smem_raw);
    double* sd = reinterpret_cast<double*>(smem_raw);
    float* Xs = sf;
    float* Ws = sf + TILE * XS_LD;

    const int b = blockIdx.y;
    const int o0 = blockIdx.x * TILE;
    const int tid = threadIdx.x;
    const int tx = tid & 15, ty = tid >> 4;

    double acc[4][4];
#pragma unroll
    for (int i = 0; i < 4; ++i)
#pragma unroll
        for (int j = 0; j < 4; ++j) acc[i][j] = 0.0;

    const int r = tid >> 3, c4 = (tid & 7) * 4;
    const float* xbase = x + (size_t)b * F_DIM;

    for (int k0 = 0; k0 < K_DIM; k0 += KC) {
        __syncthreads();
        float4 xv0 = *reinterpret_cast<const float4*>(xbase + (size_t)r * COLS + k0 + c4);
        float4 xv1 = *reinterpret_cast<const float4*>(xbase + (size_t)(r + 32) * COLS + k0 + c4);
        *reinterpret_cast<float4*>(Xs + r * XS_LD + c4) = xv0;
        *reinterpret_cast<float4*>(Xs + (r + 32) * XS_LD + c4) = xv1;
        float4 wv0 = *reinterpret_cast<const float4*>(Wm + (size_t)(o0 + r) * K_DIM + k0 + c4);
        float4 wv1 = *reinterpret_cast<const float4*>(Wm + (size_t)(o0 + r + 32) * K_DIM + k0 + c4);
        *reinterpret_cast<float4*>(Ws + r * XS_LD + c4) = wv0;
        *reinterpret_cast<float4*>(Ws + (r + 32) * XS_LD + c4) = wv1;
        __syncthreads();
#pragma unroll 4
        for (int kk = 0; kk < KC; ++kk) {
            double xa[4], wb[4];
#pragma unroll
            for (int i = 0; i < 4; ++i) xa[i] = (double)Xs[(4 * ty + i) * XS_LD + kk];
#pragma unroll
            for (int j = 0; j < 4; ++j) wb[j] = (double)Ws[(4 * tx + j) * XS_LD + kk];
#pragma unroll
            for (int i = 0; i < 4; ++i)
#pragma unroll
                for (int j = 0; j < 4; ++j) acc[i][j] = fma(xa[i], wb[j], acc[i][j]);
        }
    }
    __syncthreads();
#pragma unroll
    for (int i = 0; i < 4; ++i)
#pragma unroll
        for (int j = 0; j < 4; ++j) sd[(4 * ty + i) * SC_LD + (4 * tx + j)] = acc[i][j];
    __syncthreads();
    if (tid < TILE) {
        double v = 0.0;
        float* outp = out + (size_t)b * F_DIM + o0 + tid;
        for (int t = 0; t < T_DIM; ++t) {
            double cu = sd[t * SC_LD + tid];
            double h = v + (cu - v) * 0.5;
            bool s = (h >= 1.0);
            outp[(size_t)t * COLS] = s ? 1.0f : 0.0f;
            v = s ? 0.0 : h;
        }
    }
}

// ------------------------------------------------------------------- launch
extern "C" void kernel_launch(void* const* d_in, const int* in_sizes, int n_in,
                              void* d_out, int out_size, void* d_ws, size_t ws_size,
                              hipStream_t stream) {
    const float* x = (const float*)d_in[0];   // [64][256][1024]
    const float* Wm = (const float*)d_in[1];  // [1024][1024]
    float* out = (float*)d_out;

    // workspace layout (bytes)
    const size_t OFF_XHI = 0;
    const size_t OFF_XLO = OFF_XHI + (size_t)M_DIM * K_DIM * 2;
    const size_t OFF_WHI = OFF_XLO + (size_t)M_DIM * K_DIM * 2;
    const size_t OFF_WLO = OFF_WHI + (size_t)F_DIM * K_DIM * 2;
    const size_t OFF_CUR = OFF_WLO + (size_t)F_DIM * K_DIM * 2;
    const size_t OFF_CNT = OFF_CUR + (size_t)M_DIM * F_DIM * 4;
    const size_t OFF_LST = OFF_CNT + 256;
    const size_t NEEDED  = OFF_LST + (size_t)LIST_CAP * 4;

    if (ws_size < NEEDED) {
        // fallback: proven fp64 fused kernel
        dim3 grid(F_DIM / TILE, B_DIM, 1);
        lif_fused_kernel<<<grid, dim3(256), 0, stream>>>(x, Wm, out);
        return;
    }

    unsigned char* ws = (unsigned char*)d_ws;
    unsigned short* x_hi = (unsigned short*)(ws + OFF_XHI);
    unsigned short* x_lo = (unsigned short*)(ws + OFF_XLO);
    unsigned short* w_hi = (unsigned short*)(ws + OFF_WHI);
    unsigned short* w_lo = (unsigned short*)(ws + OFF_WLO);
    float* cur = (float*)(ws + OFF_CUR);
    unsigned int* counter = (unsigned int*)(ws + OFF_CNT);
    unsigned int* list = (unsigned int*)(ws + OFF_LST);

    split_kernel<<<dim3(M_DIM * K_DIM / 4 / 256), dim3(256), 0, stream>>>(x, x_hi, x_lo, M_DIM * K_DIM / 4);
    split_kernel<<<dim3(F_DIM * K_DIM / 4 / 256), dim3(256), 0, stream>>>(Wm, w_hi, w_lo, F_DIM * K_DIM / 4);
    gemm3_kernel<<<dim3(F_DIM / 128, M_DIM / 128), dim3(256), 0, stream>>>(x_hi, x_lo, w_hi, w_lo, cur);
    zero_counter_kernel<<<dim3(1), dim3(256), 0, stream>>>(counter);
    scan_kernel<<<dim3(COLS / 256), dim3(256), 0, stream>>>(cur, out, counter, list);
    fixup_kernel<<<dim3(256), dim3(256), 0, stream>>>(x, Wm, counter, list, out);
}

// Round 3
// 304.831 us; speedup vs baseline: 2.9330x; 1.0896x over previous
//
#include <hip/hip_runtime.h>

// LinearLIFBlock: cur = X[16384x1024] * W^T[1024x1024]; LIF scan over t (64 steps).
// R3: fused GEMM+scan. A rows reordered to (b*64+t) so one 128-row M-tile = 2
// batches x all 64 timesteps; the LIF chain runs in-register via shfl relay.
// 3-term bf16 split as single K=3072 loop over [hi|lo] buffers with offset
// replay. Margin-flagged columns (|h-1|<1.5e-4) get exact fp64 fixup.

#define T_DIM 64
#define B_DIM 256
#define F_DIM 1024
#define K_DIM 1024
#define M_DIM 16384            // T*B
#define COLS  (B_DIM * F_DIM)  // 262144 scan columns
#define KP    2048             // packed K: [hi | lo]
#define MARGIN 1.5e-4f
#define LIST_CAP 32768

typedef __attribute__((ext_vector_type(8))) short short8;
typedef __attribute__((ext_vector_type(4))) float floatx4;

#define ASYNC_CP16(gp, lp)                                                     \
    __builtin_amdgcn_global_load_lds(                                          \
        (const __attribute__((address_space(1))) unsigned int*)(gp),           \
        (__attribute__((address_space(3))) unsigned int*)(lp), 16, 0, 0)

// ---------------------------------------------------------------- bf16 split
__device__ inline unsigned short f32_to_bf16_rne(float f) {
    unsigned int u = __builtin_bit_cast(unsigned int, f);
    unsigned int r = (u + 0x7FFFu + ((u >> 16) & 1u)) >> 16;
    return (unsigned short)r;
}
__device__ inline float bf16_to_f32(unsigned short h) {
    unsigned int u = ((unsigned int)h) << 16;
    return __builtin_bit_cast(float, u);
}

// X split + row remap: in[t][b][k] -> A[(b*64+t)][k]=hi, A[(b*64+t)][1024+k]=lo
__global__ __launch_bounds__(256) void split_x_kernel(
    const float* __restrict__ in, unsigned short* __restrict__ A)
{
    int g = blockIdx.x * 256 + threadIdx.x;   // float4 index
    int e = g * 4;
    int row = e >> 10;            // t*256 + b
    int k = e & 1023;
    int orow = ((row & 255) << 6) | (row >> 8);  // b*64 + t
    float4 v = reinterpret_cast<const float4*>(in)[g];
    ushort4 h, l;
    float f;
    f = v.x; h.x = f32_to_bf16_rne(f); l.x = f32_to_bf16_rne(f - bf16_to_f32(h.x));
    f = v.y; h.y = f32_to_bf16_rne(f); l.y = f32_to_bf16_rne(f - bf16_to_f32(h.y));
    f = v.z; h.z = f32_to_bf16_rne(f); l.z = f32_to_bf16_rne(f - bf16_to_f32(h.z));
    f = v.w; h.w = f32_to_bf16_rne(f); l.w = f32_to_bf16_rne(f - bf16_to_f32(h.w));
    reinterpret_cast<ushort4*>(A)[(size_t)orow * (KP / 4) + (k >> 2)] = h;
    reinterpret_cast<ushort4*>(A)[(size_t)orow * (KP / 4) + 256 + (k >> 2)] = l;
}

// W split (no remap) + counter zero
__global__ __launch_bounds__(256) void split_w_kernel(
    const float* __restrict__ in, unsigned short* __restrict__ B,
    unsigned int* __restrict__ counter)
{
    if (blockIdx.x == 0 && threadIdx.x == 0) *counter = 0;
    int g = blockIdx.x * 256 + threadIdx.x;
    int e = g * 4;
    int row = e >> 10;
    int k = e & 1023;
    float4 v = reinterpret_cast<const float4*>(in)[g];
    ushort4 h, l;
    float f;
    f = v.x; h.x = f32_to_bf16_rne(f); l.x = f32_to_bf16_rne(f - bf16_to_f32(h.x));
    f = v.y; h.y = f32_to_bf16_rne(f); l.y = f32_to_bf16_rne(f - bf16_to_f32(h.y));
    f = v.z; h.z = f32_to_bf16_rne(f); l.z = f32_to_bf16_rne(f - bf16_to_f32(h.z));
    f = v.w; h.w = f32_to_bf16_rne(f); l.w = f32_to_bf16_rne(f - bf16_to_f32(h.w));
    reinterpret_cast<ushort4*>(B)[(size_t)row * (KP / 4) + (k >> 2)] = h;
    reinterpret_cast<ushort4*>(B)[(size_t)row * (KP / 4) + 256 + (k >> 2)] = l;
}

// ----------------------------------------------- fused MFMA GEMM + LIF scan
// Effective K=3072: seg0 = A.hi*B.hi, seg1 = A.lo*B.hi, seg2 = A.hi*B.lo
__global__ __launch_bounds__(256) void gemm_scan_kernel(
    const unsigned short* __restrict__ A,  // [16384][2048], rows b*64+t
    const unsigned short* __restrict__ B,  // [1024][2048],  rows o
    float* __restrict__ out,
    unsigned int* __restrict__ counter, unsigned int* __restrict__ list)
{
    __shared__ unsigned short As[128 * 32];  // 8 KB
    __shared__ unsigned short Bs[128 * 32];  // 8 KB

    const int tid  = threadIdx.x;
    const int lane = tid & 63;
    const int wv   = tid >> 6;
    // XCD-aware bit-permute: each XCD owns 16 contiguous M-tiles, iterates
    // nt fastest so an A-tile is reused by 8 consecutive blocks on one XCD.
    const int lid = blockIdx.x;             // 0..1023
    const int mt  = ((lid & 7) << 4) | (lid >> 6);  // 0..127 (b-pair tile)
    const int nt  = (lid >> 3) & 7;                 // 0..7
    const int m0  = mt * 128;
    const int n0  = nt * 128;
    const int wm  = (wv & 1) * 64;          // b_off*64
    const int wn  = (wv >> 1) * 64;

    floatx4 acc[4][4] = {};

    const int srow = tid >> 2;
    const int scol = (tid & 3) * 8;
    const int lrow = lane & 15;
    const int lk   = (lane >> 4) * 8;

    const unsigned short* Ab = A + (size_t)m0 * KP;
    const unsigned short* Bb = B + (size_t)n0 * KP;

    for (int k0 = 0; k0 < 3072; k0 += 32) {
        const int aoff = (k0 < 2048) ? k0 : k0 - 2048;  // seg2 replays hi
        const int boff = (k0 < 1024) ? k0 : k0 - 1024;  // seg1 replays hi
        __syncthreads();
        ASYNC_CP16(Ab + (size_t)srow * KP + aoff + scol,        As + srow * 32 + scol);
        ASYNC_CP16(Ab + (size_t)(srow + 64) * KP + aoff + scol, As + (srow + 64) * 32 + scol);
        ASYNC_CP16(Bb + (size_t)srow * KP + boff + scol,        Bs + srow * 32 + scol);
        ASYNC_CP16(Bb + (size_t)(srow + 64) * KP + boff + scol, Bs + (srow + 64) * 32 + scol);
        __syncthreads();

        short8 a[4], b[4];
#pragma unroll
        for (int i = 0; i < 4; ++i)
            a[i] = *reinterpret_cast<const short8*>(&As[(wm + i * 16 + lrow) * 32 + lk]);
#pragma unroll
        for (int j = 0; j < 4; ++j)
            b[j] = *reinterpret_cast<const short8*>(&Bs[(wn + j * 16 + lrow) * 32 + lk]);
#pragma unroll
        for (int i = 0; i < 4; ++i)
#pragma unroll
            for (int j = 0; j < 4; ++j)
                acc[i][j] = __builtin_amdgcn_mfma_f32_16x16x32_bf16(a[i], b[j], acc[i][j], 0, 0, 0);
    }

    // ---- fused LIF scan in registers ----
    // Wave owns all 64 t of batch b = mt*2 + (wv&1), columns o = n0+wn+j*16+col.
    // acc[i][j][r] = cur at t = i*16 + q*4 + r (q = lane>>4), col = lane&15.
    // Column chain hops lanes q=0..3 per 16-t block: shfl relay of v.
    const int col = lane & 15;
    const int q   = lane >> 4;
    const int b_g = mt * 2 + (wv & 1);

    unsigned int fmask = 0;
#pragma unroll
    for (int j = 0; j < 4; ++j) {
        float v = 0.f;
        bool fl = false;
#pragma unroll
        for (int i = 0; i < 4; ++i) {
#pragma unroll
            for (int qq = 0; qq < 4; ++qq) {
                if (q == qq) {
#pragma unroll
                    for (int r = 0; r < 4; ++r) {
                        float cu = acc[i][j][r];
                        float h = v + (cu - v) * 0.5f;
                        float d = h - 1.0f;
                        bool sp = (d >= 0.f);
                        fl |= (fabsf(d) < MARGIN);
                        acc[i][j][r] = sp ? 1.0f : 0.0f;  // spike overwrites cur
                        v = sp ? 0.f : h;
                    }
                }
                v = __shfl(v, qq * 16 + col, 64);  // broadcast owner's v
            }
        }
        if (fl) fmask |= (1u << j);
    }
    fmask |= __shfl_xor(fmask, 16, 64);
    fmask |= __shfl_xor(fmask, 32, 64);

    // spike stores: same coalescing pattern as the R2 cur-epilogue
    float* outp = out + (size_t)b_g * F_DIM;
#pragma unroll
    for (int i = 0; i < 4; ++i)
#pragma unroll
        for (int j = 0; j < 4; ++j)
#pragma unroll
            for (int r = 0; r < 4; ++r) {
                int t = i * 16 + q * 4 + r;
                int o = n0 + wn + j * 16 + col;
                outp[(size_t)t * COLS + o] = acc[i][j][r];
            }

    if (q == 0 && fmask) {
        for (int j = 0; j < 4; ++j)
            if (fmask & (1u << j)) {
                unsigned int idx = atomicAdd(counter, 1u);
                if (idx < LIST_CAP)
                    list[idx] = (unsigned int)(b_g * F_DIM + n0 + wn + j * 16 + col);
            }
    }
}

// ------------------------------------------------------- exact fp64 fixup
__global__ __launch_bounds__(256) void fixup_kernel(
    const float* __restrict__ x, const float* __restrict__ W,
    const unsigned int* __restrict__ counter, const unsigned int* __restrict__ list,
    float* __restrict__ out)
{
    __shared__ double curd[T_DIM];
    __shared__ float wrow[K_DIM];
    unsigned int n = *counter;
    if (n > LIST_CAP) n = LIST_CAP;
    const int wv = threadIdx.x >> 6, lane = threadIdx.x & 63;

    for (unsigned int idx = blockIdx.x; idx < n; idx += gridDim.x) {
        const unsigned int c = list[idx];
        const int b = c >> 10, o = c & 1023;
        __syncthreads();
        for (int k = threadIdx.x; k < K_DIM; k += 256) wrow[k] = W[(size_t)o * K_DIM + k];
        __syncthreads();
        for (int it = 0; it < 16; ++it) {
            const int t = it * 4 + wv;
            const float* xp = x + (size_t)t * COLS + (size_t)b * F_DIM + lane * 16;
            const float* wp = wrow + lane * 16;
            double s = 0.0;
#pragma unroll
            for (int qq = 0; qq < 4; ++qq) {
                float4 xv = reinterpret_cast<const float4*>(xp)[qq];
                float4 wq = reinterpret_cast<const float4*>(wp)[qq];
                s += (double)xv.x * (double)wq.x + (double)xv.y * (double)wq.y +
                     (double)xv.z * (double)wq.z + (double)xv.w * (double)wq.w;
            }
#pragma unroll
            for (int off = 32; off > 0; off >>= 1) s += __shfl_down(s, off, 64);
            if (lane == 0) curd[t] = s;
        }
        __syncthreads();
        if (threadIdx.x == 0) {
            double v = 0.0;
            for (int t = 0; t < T_DIM; ++t) {
                double h = v + (curd[t] - v) * 0.5;
                bool s = (h >= 1.0);
                out[(size_t)t * COLS + c] = s ? 1.0f : 0.0f;
                v = s ? 0.0 : h;
            }
        }
        __syncthreads();
    }
}

// --------------------------------------------------- fp64 fallback (round-1)
#define TILE 64
#define KC 32
#define XS_LD 36
#define SC_LD 65

__global__ __launch_bounds__(256) void lif_fused_kernel(
    const float* __restrict__ x, const float* __restrict__ Wm, float* __restrict__ out)
{
    __shared__ __align__(16) unsigned char smem_raw[TILE * SC_LD * sizeof(double)];
    float* sf = reinterpret_cast<float*>(smem_raw);
    double* sd = reinterpret_cast<double*>(smem_raw);
    float* Xs = sf;
    float* Ws = sf + TILE * XS_LD;

    const int b = blockIdx.y;
    const int o0 = blockIdx.x * TILE;
    const int tid = threadIdx.x;
    const int tx = tid & 15, ty = tid >> 4;

    double acc[4][4];
#pragma unroll
    for (int i = 0; i < 4; ++i)
#pragma unroll
        for (int j = 0; j < 4; ++j) acc[i][j] = 0.0;

    const int r = tid >> 3, c4 = (tid & 7) * 4;
    const float* xbase = x + (size_t)b * F_DIM;

    for (int k0 = 0; k0 < K_DIM; k0 += KC) {
        __syncthreads();
        float4 xv0 = *reinterpret_cast<const float4*>(xbase + (size_t)r * COLS + k0 + c4);
        float4 xv1 = *reinterpret_cast<const float4*>(xbase + (size_t)(r + 32) * COLS + k0 + c4);
        *reinterpret_cast<float4*>(Xs + r * XS_LD + c4) = xv0;
        *reinterpret_cast<float4*>(Xs + (r + 32) * XS_LD + c4) = xv1;
        float4 wv0 = *reinterpret_cast<const float4*>(Wm + (size_t)(o0 + r) * K_DIM + k0 + c4);
        float4 wv1 = *reinterpret_cast<const float4*>(Wm + (size_t)(o0 + r + 32) * K_DIM + k0 + c4);
        *reinterpret_cast<float4*>(Ws + r * XS_LD + c4) = wv0;
        *reinterpret_cast<float4*>(Ws + (r + 32) * XS_LD + c4) = wv1;
        __syncthreads();
#pragma unroll 4
        for (int kk = 0; kk < KC; ++kk) {
            double xa[4], wb[4];
#pragma unroll
            for (int i = 0; i < 4; ++i) xa[i] = (double)Xs[(4 * ty + i) * XS_LD + kk];
#pragma unroll
            for (int j = 0; j < 4; ++j) wb[j] = (double)Ws[(4 * tx + j) * XS_LD + kk];
#pragma unroll
            for (int i = 0; i < 4; ++i)
#pragma unroll
                for (int j = 0; j < 4; ++j) acc[i][j] = fma(xa[i], wb[j], acc[i][j]);
        }
    }
    __syncthreads();
#pragma unroll
    for (int i = 0; i < 4; ++i)
#pragma unroll
        for (int j = 0; j < 4; ++j) sd[(4 * ty + i) * SC_LD + (4 * tx + j)] = acc[i][j];
    __syncthreads();
    if (tid < TILE) {
        double v = 0.0;
        float* outp = out + (size_t)b * F_DIM + o0 + tid;
        for (int t = 0; t < T_DIM; ++t) {
            double cu = sd[t * SC_LD + tid];
            double h = v + (cu - v) * 0.5;
            bool s = (h >= 1.0);
            outp[(size_t)t * COLS] = s ? 1.0f : 0.0f;
            v = s ? 0.0 : h;
        }
    }
}

// ------------------------------------------------------------------- launch
extern "C" void kernel_launch(void* const* d_in, const int* in_sizes, int n_in,
                              void* d_out, int out_size, void* d_ws, size_t ws_size,
                              hipStream_t stream) {
    const float* x = (const float*)d_in[0];   // [64][256][1024]
    const float* Wm = (const float*)d_in[1];  // [1024][1024]
    float* out = (float*)d_out;

    const size_t OFF_A   = 0;                                   // 64 MB
    const size_t OFF_B   = OFF_A + (size_t)M_DIM * KP * 2;      // 4 MB
    const size_t OFF_CNT = OFF_B + (size_t)F_DIM * KP * 2;
    const size_t OFF_LST = OFF_CNT + 256;
    const size_t NEEDED  = OFF_LST + (size_t)LIST_CAP * 4;

    if (ws_size < NEEDED) {
        dim3 grid(F_DIM / TILE, B_DIM, 1);
        lif_fused_kernel<<<grid, dim3(256), 0, stream>>>(x, Wm, out);
        return;
    }

    unsigned char* ws = (unsigned char*)d_ws;
    unsigned short* Abuf = (unsigned short*)(ws + OFF_A);
    unsigned short* Bbuf = (unsigned short*)(ws + OFF_B);
    unsigned int* counter = (unsigned int*)(ws + OFF_CNT);
    unsigned int* list = (unsigned int*)(ws + OFF_LST);

    split_x_kernel<<<dim3(M_DIM * K_DIM / 4 / 256), dim3(256), 0, stream>>>(x, Abuf);
    split_w_kernel<<<dim3(F_DIM * K_DIM / 4 / 256), dim3(256), 0, stream>>>(Wm, Bbuf, counter);
    gemm_scan_kernel<<<dim3(1024), dim3(256), 0, stream>>>(Abuf, Bbuf, out, counter, list);
    fixup_kernel<<<dim3(256), dim3(256), 0, stream>>>(x, Wm, counter, list, out);
}

// Round 4
// 273.518 us; speedup vs baseline: 3.2688x; 1.1145x over previous
//
#include <hip/hip_runtime.h>

// LinearLIFBlock: cur = X[16384x1024] * W^T[1024x1024]; LIF scan over t (64 steps).
// R4: 128x256 block tile, grid=512 (exactly 2 blocks/CU -> no tail), wave-tile
// 64x128 (acc[4][8]) to raise FLOP per LDS-byte 21.8->28.4. A rows remapped to
// (b*64+t); in-register LIF via shfl relay (validated R3). 3-term bf16 split as
// single K=3072 loop; margin-flagged columns (|h-1|<1.5e-4) get exact fp64 fixup.

#define T_DIM 64
#define B_DIM 256
#define F_DIM 1024
#define K_DIM 1024
#define M_DIM 16384            // T*B
#define COLS  (B_DIM * F_DIM)  // 262144 scan columns
#define KP    2048             // packed K: [hi | lo]
#define MARGIN 1.5e-4f
#define LIST_CAP 32768

typedef __attribute__((ext_vector_type(8))) short short8;
typedef __attribute__((ext_vector_type(4))) float floatx4;

#define ASYNC_CP16(gp, lp)                                                     \
    __builtin_amdgcn_global_load_lds(                                          \
        (const __attribute__((address_space(1))) unsigned int*)(gp),           \
        (__attribute__((address_space(3))) unsigned int*)(lp), 16, 0, 0)

// ---------------------------------------------------------------- bf16 split
__device__ inline unsigned short f32_to_bf16_rne(float f) {
    unsigned int u = __builtin_bit_cast(unsigned int, f);
    unsigned int r = (u + 0x7FFFu + ((u >> 16) & 1u)) >> 16;
    return (unsigned short)r;
}
__device__ inline float bf16_to_f32(unsigned short h) {
    unsigned int u = ((unsigned int)h) << 16;
    return __builtin_bit_cast(float, u);
}

// X split + row remap: in[t][b][k] -> A[(b*64+t)][k]=hi, A[(b*64+t)][1024+k]=lo
__global__ __launch_bounds__(256) void split_x_kernel(
    const float* __restrict__ in, unsigned short* __restrict__ A)
{
    int g = blockIdx.x * 256 + threadIdx.x;   // float4 index
    int e = g * 4;
    int row = e >> 10;            // t*256 + b
    int k = e & 1023;
    int orow = ((row & 255) << 6) | (row >> 8);  // b*64 + t
    float4 v = reinterpret_cast<const float4*>(in)[g];
    ushort4 h, l;
    float f;
    f = v.x; h.x = f32_to_bf16_rne(f); l.x = f32_to_bf16_rne(f - bf16_to_f32(h.x));
    f = v.y; h.y = f32_to_bf16_rne(f); l.y = f32_to_bf16_rne(f - bf16_to_f32(h.y));
    f = v.z; h.z = f32_to_bf16_rne(f); l.z = f32_to_bf16_rne(f - bf16_to_f32(h.z));
    f = v.w; h.w = f32_to_bf16_rne(f); l.w = f32_to_bf16_rne(f - bf16_to_f32(h.w));
    reinterpret_cast<ushort4*>(A)[(size_t)orow * (KP / 4) + (k >> 2)] = h;
    reinterpret_cast<ushort4*>(A)[(size_t)orow * (KP / 4) + 256 + (k >> 2)] = l;
}

// W split (no remap) + counter zero
__global__ __launch_bounds__(256) void split_w_kernel(
    const float* __restrict__ in, unsigned short* __restrict__ B,
    unsigned int* __restrict__ counter)
{
    if (blockIdx.x == 0 && threadIdx.x == 0) *counter = 0;
    int g = blockIdx.x * 256 + threadIdx.x;
    int e = g * 4;
    int row = e >> 10;
    int k = e & 1023;
    float4 v = reinterpret_cast<const float4*>(in)[g];
    ushort4 h, l;
    float f;
    f = v.x; h.x = f32_to_bf16_rne(f); l.x = f32_to_bf16_rne(f - bf16_to_f32(h.x));
    f = v.y; h.y = f32_to_bf16_rne(f); l.y = f32_to_bf16_rne(f - bf16_to_f32(h.y));
    f = v.z; h.z = f32_to_bf16_rne(f); l.z = f32_to_bf16_rne(f - bf16_to_f32(h.z));
    f = v.w; h.w = f32_to_bf16_rne(f); l.w = f32_to_bf16_rne(f - bf16_to_f32(h.w));
    reinterpret_cast<ushort4*>(B)[(size_t)row * (KP / 4) + (k >> 2)] = h;
    reinterpret_cast<ushort4*>(B)[(size_t)row * (KP / 4) + 256 + (k >> 2)] = l;
}

// ----------------------------------------------- fused MFMA GEMM + LIF scan
// Block tile 128(M) x 256(N); effective K=3072:
//   seg0 = A.hi*B.hi, seg1 = A.lo*B.hi, seg2 = A.hi*B.lo
__global__ __launch_bounds__(256, 2) void gemm_scan_kernel(
    const unsigned short* __restrict__ A,  // [16384][2048], rows b*64+t
    const unsigned short* __restrict__ B,  // [1024][2048],  rows o
    float* __restrict__ out,
    unsigned int* __restrict__ counter, unsigned int* __restrict__ list)
{
    __shared__ unsigned short As[128 * 32];  // 8 KB
    __shared__ unsigned short Bs[256 * 32];  // 16 KB

    const int tid  = threadIdx.x;
    const int lane = tid & 63;
    const int wv   = tid >> 6;
    // XCD-aware: XCD = lid&7 owns a contiguous 16-mt stripe; nt varies fastest.
    const int lid = blockIdx.x;                      // 0..511
    const int mt  = ((lid & 7) << 4) | (lid >> 5);   // 0..127
    const int nt  = (lid >> 3) & 3;                  // 0..3
    const int m0  = mt * 128;
    const int n0  = nt * 256;
    const int wm  = (wv & 1) * 64;
    const int wn  = (wv >> 1) * 128;

    floatx4 acc[4][8] = {};

    const int srow = tid >> 2;            // 0..63
    const int scol = (tid & 3) * 8;       // bf16 offset (16B chunks)
    const int lrow = lane & 15;
    const int lk   = (lane >> 4) * 8;

    const unsigned short* Ab = A + (size_t)m0 * KP;
    const unsigned short* Bb = B + (size_t)n0 * KP;

    for (int k0 = 0; k0 < 3072; k0 += 32) {
        const int aoff = (k0 < 2048) ? k0 : k0 - 2048;  // seg2 replays hi
        const int boff = (k0 < 1024) ? k0 : k0 - 1024;  // seg1 replays hi
        __syncthreads();
        ASYNC_CP16(Ab + (size_t)srow * KP + aoff + scol,         As + srow * 32 + scol);
        ASYNC_CP16(Ab + (size_t)(srow + 64) * KP + aoff + scol,  As + (srow + 64) * 32 + scol);
        ASYNC_CP16(Bb + (size_t)srow * KP + boff + scol,         Bs + srow * 32 + scol);
        ASYNC_CP16(Bb + (size_t)(srow + 64) * KP + boff + scol,  Bs + (srow + 64) * 32 + scol);
        ASYNC_CP16(Bb + (size_t)(srow + 128) * KP + boff + scol, Bs + (srow + 128) * 32 + scol);
        ASYNC_CP16(Bb + (size_t)(srow + 192) * KP + boff + scol, Bs + (srow + 192) * 32 + scol);
        __syncthreads();

        short8 a[4], b[8];
#pragma unroll
        for (int i = 0; i < 4; ++i)
            a[i] = *reinterpret_cast<const short8*>(&As[(wm + i * 16 + lrow) * 32 + lk]);
#pragma unroll
        for (int j = 0; j < 8; ++j)
            b[j] = *reinterpret_cast<const short8*>(&Bs[(wn + j * 16 + lrow) * 32 + lk]);
#pragma unroll
        for (int i = 0; i < 4; ++i)
#pragma unroll
            for (int j = 0; j < 8; ++j)
                acc[i][j] = __builtin_amdgcn_mfma_f32_16x16x32_bf16(a[i], b[j], acc[i][j], 0, 0, 0);
    }

    // ---- fused LIF scan in registers (validated relay, j extended to 8) ----
    // Wave owns all 64 t of batch b = mt*2 + (wv&1), cols o = n0+wn+j*16+col.
    // acc[i][j][r] = cur at t = i*16 + q*4 + r (q = lane>>4), col = lane&15.
    const int col = lane & 15;
    const int q   = lane >> 4;
    const int b_g = mt * 2 + (wv & 1);

    unsigned int fmask = 0;
#pragma unroll
    for (int j = 0; j < 8; ++j) {
        float v = 0.f;
        bool fl = false;
#pragma unroll
        for (int i = 0; i < 4; ++i) {
#pragma unroll
            for (int qq = 0; qq < 4; ++qq) {
                if (q == qq) {
#pragma unroll
                    for (int r = 0; r < 4; ++r) {
                        float cu = acc[i][j][r];
                        float h = v + (cu - v) * 0.5f;
                        float d = h - 1.0f;
                        bool sp = (d >= 0.f);
                        fl |= (fabsf(d) < MARGIN);
                        acc[i][j][r] = sp ? 1.0f : 0.0f;  // spike overwrites cur
                        v = sp ? 0.f : h;
                    }
                }
                v = __shfl(v, qq * 16 + col, 64);  // broadcast owner's v
            }
        }
        if (fl) fmask |= (1u << j);
    }
    fmask |= __shfl_xor(fmask, 16, 64);
    fmask |= __shfl_xor(fmask, 32, 64);

    // spike stores
    float* outp = out + (size_t)b_g * F_DIM;
#pragma unroll
    for (int i = 0; i < 4; ++i)
#pragma unroll
        for (int j = 0; j < 8; ++j)
#pragma unroll
            for (int r = 0; r < 4; ++r) {
                int t = i * 16 + q * 4 + r;
                int o = n0 + wn + j * 16 + col;
                outp[(size_t)t * COLS + o] = acc[i][j][r];
            }

    if (q == 0 && fmask) {
        for (int j = 0; j < 8; ++j)
            if (fmask & (1u << j)) {
                unsigned int idx = atomicAdd(counter, 1u);
                if (idx < LIST_CAP)
                    list[idx] = (unsigned int)(b_g * F_DIM + n0 + wn + j * 16 + col);
            }
    }
}

// ------------------------------------------------------- exact fp64 fixup
__global__ __launch_bounds__(256) void fixup_kernel(
    const float* __restrict__ x, const float* __restrict__ W,
    const unsigned int* __restrict__ counter, const unsigned int* __restrict__ list,
    float* __restrict__ out)
{
    __shared__ double curd[T_DIM];
    __shared__ float wrow[K_DIM];
    unsigned int n = *counter;
    if (n > LIST_CAP) n = LIST_CAP;
    const int wv = threadIdx.x >> 6, lane = threadIdx.x & 63;

    for (unsigned int idx = blockIdx.x; idx < n; idx += gridDim.x) {
        const unsigned int c = list[idx];
        const int b = c >> 10, o = c & 1023;
        __syncthreads();
        for (int k = threadIdx.x; k < K_DIM; k += 256) wrow[k] = W[(size_t)o * K_DIM + k];
        __syncthreads();
        for (int it = 0; it < 16; ++it) {
            const int t = it * 4 + wv;
            const float* xp = x + (size_t)t * COLS + (size_t)b * F_DIM + lane * 16;
            const float* wp = wrow + lane * 16;
            double s = 0.0;
#pragma unroll
            for (int qq = 0; qq < 4; ++qq) {
                float4 xv = reinterpret_cast<const float4*>(xp)[qq];
                float4 wq = reinterpret_cast<const float4*>(wp)[qq];
                s += (double)xv.x * (double)wq.x + (double)xv.y * (double)wq.y +
                     (double)xv.z * (double)wq.z + (double)xv.w * (double)wq.w;
            }
#pragma unroll
            for (int off = 32; off > 0; off >>= 1) s += __shfl_down(s, off, 64);
            if (lane == 0) curd[t] = s;
        }
        __syncthreads();
        if (threadIdx.x == 0) {
            double v = 0.0;
            for (int t = 0; t < T_DIM; ++t) {
                double h = v + (curd[t] - v) * 0.5;
                bool s = (h >= 1.0);
                out[(size_t)t * COLS + c] = s ? 1.0f : 0.0f;
                v = s ? 0.0 : h;
            }
        }
        __syncthreads();
    }
}

// --------------------------------------------------- fp64 fallback (round-1)
#define TILE 64
#define KC 32
#define XS_LD 36
#define SC_LD 65

__global__ __launch_bounds__(256) void lif_fused_kernel(
    const float* __restrict__ x, const float* __restrict__ Wm, float* __restrict__ out)
{
    __shared__ __align__(16) unsigned char smem_raw[TILE * SC_LD * sizeof(double)];
    float* sf = reinterpret_cast<float*>(smem_raw);
    double* sd = reinterpret_cast<double*>(smem_raw);
    float* Xs = sf;
    float* Ws = sf + TILE * XS_LD;

    const int b = blockIdx.y;
    const int o0 = blockIdx.x * TILE;
    const int tid = threadIdx.x;
    const int tx = tid & 15, ty = tid >> 4;

    double acc[4][4];
#pragma unroll
    for (int i = 0; i < 4; ++i)
#pragma unroll
        for (int j = 0; j < 4; ++j) acc[i][j] = 0.0;

    const int r = tid >> 3, c4 = (tid & 7) * 4;
    const float* xbase = x + (size_t)b * F_DIM;

    for (int k0 = 0; k0 < K_DIM; k0 += KC) {
        __syncthreads();
        float4 xv0 = *reinterpret_cast<const float4*>(xbase + (size_t)r * COLS + k0 + c4);
        float4 xv1 = *reinterpret_cast<const float4*>(xbase + (size_t)(r + 32) * COLS + k0 + c4);
        *reinterpret_cast<float4*>(Xs + r * XS_LD + c4) = xv0;
        *reinterpret_cast<float4*>(Xs + (r + 32) * XS_LD + c4) = xv1;
        float4 wv0 = *reinterpret_cast<const float4*>(Wm + (size_t)(o0 + r) * K_DIM + k0 + c4);
        float4 wv1 = *reinterpret_cast<const float4*>(Wm + (size_t)(o0 + r + 32) * K_DIM + k0 + c4);
        *reinterpret_cast<float4*>(Ws + r * XS_LD + c4) = wv0;
        *reinterpret_cast<float4*>(Ws + (r + 32) * XS_LD + c4) = wv1;
        __syncthreads();
#pragma unroll 4
        for (int kk = 0; kk < KC; ++kk) {
            double xa[4], wb[4];
#pragma unroll
            for (int i = 0; i < 4; ++i) xa[i] = (double)Xs[(4 * ty + i) * XS_LD + kk];
#pragma unroll
            for (int j = 0; j < 4; ++j) wb[j] = (double)Ws[(4 * tx + j) * XS_LD + kk];
#pragma unroll
            for (int i = 0; i < 4; ++i)
#pragma unroll
                for (int j = 0; j < 4; ++j) acc[i][j] = fma(xa[i], wb[j], acc[i][j]);
        }
    }
    __syncthreads();
#pragma unroll
    for (int i = 0; i < 4; ++i)
#pragma unroll
        for (int j = 0; j < 4; ++j) sd[(4 * ty + i) * SC_LD + (4 * tx + j)] = acc[i][j];
    __syncthreads();
    if (tid < TILE) {
        double v = 0.0;
        float* outp = out + (size_t)b * F_DIM + o0 + tid;
        for (int t = 0; t < T_DIM; ++t) {
            double cu = sd[t * SC_LD + tid];
            double h = v + (cu - v) * 0.5;
            bool s = (h >= 1.0);
            outp[(size_t)t * COLS] = s ? 1.0f : 0.0f;
            v = s ? 0.0 : h;
        }
    }
}

// ------------------------------------------------------------------- launch
extern "C" void kernel_launch(void* const* d_in, const int* in_sizes, int n_in,
                              void* d_out, int out_size, void* d_ws, size_t ws_size,
                              hipStream_t stream) {
    const float* x = (const float*)d_in[0];   // [64][256][1024]
    const float* Wm = (const float*)d_in[1];  // [1024][1024]
    float* out = (float*)d_out;

    const size_t OFF_A   = 0;                                   // 64 MB
    const size_t OFF_B   = OFF_A + (size_t)M_DIM * KP * 2;      // 4 MB
    const size_t OFF_CNT = OFF_B + (size_t)F_DIM * KP * 2;
    const size_t OFF_LST = OFF_CNT + 256;
    const size_t NEEDED  = OFF_LST + (size_t)LIST_CAP * 4;

    if (ws_size < NEEDED) {
        dim3 grid(F_DIM / TILE, B_DIM, 1);
        lif_fused_kernel<<<grid, dim3(256), 0, stream>>>(x, Wm, out);
        return;
    }

    unsigned char* ws = (unsigned char*)d_ws;
    unsigned short* Abuf = (unsigned short*)(ws + OFF_A);
    unsigned short* Bbuf = (unsigned short*)(ws + OFF_B);
    unsigned int* counter = (unsigned int*)(ws + OFF_CNT);
    unsigned int* list = (unsigned int*)(ws + OFF_LST);

    split_x_kernel<<<dim3(M_DIM * K_DIM / 4 / 256), dim3(256), 0, stream>>>(x, Abuf);
    split_w_kernel<<<dim3(F_DIM * K_DIM / 4 / 256), dim3(256), 0, stream>>>(Wm, Bbuf, counter);
    gemm_scan_kernel<<<dim3(512), dim3(256), 0, stream>>>(Abuf, Bbuf, out, counter, list);
    fixup_kernel<<<dim3(512), dim3(256), 0, stream>>>(x, Wm, counter, list, out);
}